// Round 2
// baseline (1346.681 us; speedup 1.0000x reference)
//
#include <hip/hip_runtime.h>

#define W_DIM   512
#define IN_CH   512
#define OUT_CH  3
#define HW      16384          // 128*128
#define BATCH   32
#define CLAMP_V 256.0f
#define SPLIT   8
#define CH_PER  (IN_CH / SPLIT)   // 64 channels per split block

// gain = 1/sqrt(512) for both fc_gain and weight_gain
#define GAIN 0.04419417382415922f

// ---------------------------------------------------------------------------
// Kernel 1: one wave per (b, i) pair.
//   styles[b][i] = (dot(w[b,:], aw[i,:]) * GAIN + ab[i]) * GAIN
//   m[b][o][i]   = wk[o][i] * styles[b][i]
// ---------------------------------------------------------------------------
__global__ __launch_bounds__(256) void styles_kernel(
    const float* __restrict__ w,    // [32, 512]
    const float* __restrict__ aw,   // [512, 512]
    const float* __restrict__ ab,   // [512]
    const float* __restrict__ wk,   // [3, 512]
    float* __restrict__ m)          // [32, 3, 512] workspace
{
    const int wid  = blockIdx.x * (blockDim.x >> 6) + (threadIdx.x >> 6);
    const int lane = threadIdx.x & 63;
    const int b = wid >> 9;
    const int i = wid & 511;

    const float* wrow = w  + b * W_DIM;
    const float* arow = aw + i * W_DIM;

    float sum = 0.0f;
    #pragma unroll
    for (int k = lane; k < W_DIM; k += 64)
        sum += wrow[k] * arow[k];

    #pragma unroll
    for (int off = 32; off > 0; off >>= 1)
        sum += __shfl_xor(sum, off, 64);

    const float style = (sum * GAIN + ab[i]) * GAIN;

    if (lane < OUT_CH)
        m[(b * OUT_CH + lane) * IN_CH + i] = wk[lane * IN_CH + i] * style;
}

// ---------------------------------------------------------------------------
// Kernel 2: K-split modulated 1x1 conv. Each block: one channel-split s
// (64 channels) of one batch's pixel slice. Writes fp32 partial planes.
// Grid: SPLIT * BATCH * 16 = 4096 blocks -> 4 blocks/CU resident, 16 waves/CU.
// ---------------------------------------------------------------------------
__global__ __launch_bounds__(256, 4) void torgb_part(
    const float* __restrict__ x,     // [32, 512, 16384]
    const float* __restrict__ m,     // [32, 3, 512]
    float* __restrict__ part)        // [SPLIT, 32, 3, 16384]
{
    __shared__ float sm[OUT_CH * CH_PER];   // 192 floats

    const int idx = blockIdx.x;
    const int blk = idx & 15;          // pixel slice
    const int b   = (idx >> 4) & 31;   // batch
    const int s   = idx >> 9;          // channel split

    // stage this block's slice of modulated weights into LDS
    if (threadIdx.x < OUT_CH * CH_PER) {
        const int o = threadIdx.x / CH_PER;
        const int i = threadIdx.x % CH_PER;
        sm[threadIdx.x] = m[(b * OUT_CH + o) * IN_CH + s * CH_PER + i];
    }
    __syncthreads();

    const int p4 = blk * 256 + threadIdx.x;   // float4 index in plane
    const float4* xb = (const float4*)(x + ((size_t)b * IN_CH + s * CH_PER) * HW) + p4;

    float4 a0 = {0.f, 0.f, 0.f, 0.f};
    float4 a1 = {0.f, 0.f, 0.f, 0.f};
    float4 a2 = {0.f, 0.f, 0.f, 0.f};

    #pragma unroll 8
    for (int i = 0; i < CH_PER; ++i) {
        const float4 xv = xb[i * (HW / 4)];
        const float m0 = sm[i];
        const float m1 = sm[CH_PER + i];
        const float m2 = sm[2 * CH_PER + i];
        a0.x = fmaf(xv.x, m0, a0.x); a0.y = fmaf(xv.y, m0, a0.y);
        a0.z = fmaf(xv.z, m0, a0.z); a0.w = fmaf(xv.w, m0, a0.w);
        a1.x = fmaf(xv.x, m1, a1.x); a1.y = fmaf(xv.y, m1, a1.y);
        a1.z = fmaf(xv.z, m1, a1.z); a1.w = fmaf(xv.w, m1, a1.w);
        a2.x = fmaf(xv.x, m2, a2.x); a2.y = fmaf(xv.y, m2, a2.y);
        a2.z = fmaf(xv.z, m2, a2.z); a2.w = fmaf(xv.w, m2, a2.w);
    }

    float4* pb = (float4*)(part + ((size_t)(s * BATCH + b) * OUT_CH) * HW) + p4;
    pb[0]            = a0;
    pb[HW / 4]       = a1;
    pb[2 * (HW / 4)] = a2;
}

// ---------------------------------------------------------------------------
// Kernel 3: sum the SPLIT partials, add bias, clamp, store.
// out float4 count = 32*3*4096 = 393216 -> 1536 blocks * 256 threads.
// ---------------------------------------------------------------------------
__global__ __launch_bounds__(256) void combine_kernel(
    const float* __restrict__ part,  // [SPLIT, 32, 3, 16384]
    const float* __restrict__ bias,  // [3]
    float* __restrict__ out)         // [32, 3, 16384]
{
    const int j = blockIdx.x * 256 + threadIdx.x;       // float4 index over out
    const int PLANE4 = BATCH * OUT_CH * (HW / 4);       // 393216

    const float4* p4 = (const float4*)part;
    float4 acc = p4[j];
    #pragma unroll
    for (int s = 1; s < SPLIT; ++s) {
        const float4 v = p4[s * PLANE4 + j];
        acc.x += v.x; acc.y += v.y; acc.z += v.z; acc.w += v.w;
    }

    const int o = (j >> 12) % OUT_CH;                   // j / 4096 % 3
    const float bb = bias[o];

    float4 r;
    r.x = fminf(fmaxf(acc.x + bb, -CLAMP_V), CLAMP_V);
    r.y = fminf(fmaxf(acc.y + bb, -CLAMP_V), CLAMP_V);
    r.z = fminf(fmaxf(acc.z + bb, -CLAMP_V), CLAMP_V);
    r.w = fminf(fmaxf(acc.w + bb, -CLAMP_V), CLAMP_V);
    ((float4*)out)[j] = r;
}

extern "C" void kernel_launch(void* const* d_in, const int* in_sizes, int n_in,
                              void* d_out, int out_size, void* d_ws, size_t ws_size,
                              hipStream_t stream) {
    const float* x    = (const float*)d_in[0];
    const float* w    = (const float*)d_in[1];
    const float* aw   = (const float*)d_in[2];
    const float* ab   = (const float*)d_in[3];
    const float* wk   = (const float*)d_in[4];
    const float* bias = (const float*)d_in[5];
    float* out = (float*)d_out;

    // workspace layout: m [32*3*512] floats, then partials [8*32*3*16384] floats
    float* m    = (float*)d_ws;
    float* part = m + BATCH * OUT_CH * IN_CH;

    styles_kernel<<<BATCH * IN_CH / 4, 256, 0, stream>>>(w, aw, ab, wk, m);
    torgb_part<<<SPLIT * BATCH * 16, 256, 0, stream>>>(x, m, part);
    combine_kernel<<<BATCH * OUT_CH * (HW / 4) / 256, 256, 0, stream>>>(part, bias, out);
}